// Round 6
// baseline (752.514 us; speedup 1.0000x reference)
//
#include <hip/hip_runtime.h>

#define N_PATHS 8192
#define T_STEPS 256
#define D_IN    44
#define H_SZ    8
#define G4      32      // 4*H
#define NGROUPS 1024
#define TC      16      // timesteps per chunk

// ---------------- workspace layout (floats) ----------------
// [0, 1408)            Wt   : W_ih transposed+gate-permuted [d][u*4+m]
// [1408, 1440)         bias : b_ih + b_hh (gate-permuted, u*4+m)
// [1440, 1440+8192)    perm : path ids sorted by last_idx (int)
// [9632, 9632+8192)    s    : per-path score dot(h_last, fc_W)

__device__ __forceinline__ float sigm_f(float x) {
    return __builtin_amdgcn_rcpf(1.0f + __expf(-x));
}
__device__ __forceinline__ float tanh_f(float x) {
    return 1.0f - 2.0f * __builtin_amdgcn_rcpf(1.0f + __expf(2.0f * x));
}

// ---------------- prep: permuted transpose + counting sort by last_idx ----------------
__global__ void prep_kernel(const float* __restrict__ W_ih, const float* __restrict__ b_ih,
                            const float* __restrict__ b_hh, const int* __restrict__ last_idx,
                            float* __restrict__ Wt, float* __restrict__ bias,
                            int* __restrict__ perm) {
    __shared__ int hist[256];
    __shared__ int off[256];
    const int tid = threadIdx.x;  // 256 threads
    hist[tid] = 0;
    // transpose W_ih [32][44] -> Wt [44][32], gate index permuted to UNIT-MAJOR:
    // row g = m*8+u  ->  column u*4+m. REQUIRED by phase-2's float4 read at 4*j
    // (this pairing was broken in the round-5 regression; restored here).
    for (int idx = tid; idx < G4 * D_IN; idx += 256) {
        int g = idx / D_IN, d = idx - g * D_IN;
        int gp = ((g & 7) << 2) | (g >> 3);   // u*4 + m
        Wt[d * G4 + gp] = W_ih[idx];
    }
    if (tid < G4) {
        int gp = ((tid & 7) << 2) | (tid >> 3);
        bias[gp] = b_ih[tid] + b_hh[tid];
    }
    __syncthreads();
    for (int k = 0; k < N_PATHS / 256; ++k)
        atomicAdd(&hist[last_idx[k * 256 + tid]], 1);
    __syncthreads();
    if (tid == 0) {  // serial exclusive scan over 256 bins: trivial cost
        int run = 0;
        for (int i = 0; i < 256; ++i) { off[i] = run; run += hist[i]; }
    }
    __syncthreads();
    for (int k = 0; k < N_PATHS / 256; ++k) {
        int p = k * 256 + tid;
        int b = last_idx[p];
        int pos = atomicAdd(&off[b], 1);
        perm[pos] = p;   // order within a length-bin is arbitrary; harmless
    }
}

// ---------------- main fused LSTM kernel ----------------
// 1 wave per block, 4 length-sorted paths per wave, no __syncthreads needed
// (single wave: LDS ops complete in order within a wave).
// THEORY UNDER TEST: Wt+bias staged into LDS once per block; phase-1 inner loop
// reads them as uniform-address ds_read_b128 broadcasts. Round-3 counters implied
// ~6000 issue-slots/chunk vs ~2400 modeled — consistent with Wt[d*32+g] being
// emitted as ~1400 per-lane global loads + addressing per chunk. 352 broadcast
// ds_read_b128 replace that entirely.
__global__ __launch_bounds__(64, 1)
void lstm_kernel(const float* __restrict__ x, const float* __restrict__ Whh,
                 const float* __restrict__ Wt, const float* __restrict__ bias,
                 const float* __restrict__ fcW, const int* __restrict__ last_idx,
                 const int* __restrict__ perm, float* __restrict__ sout) {
    // xg2[tc][pl*40 + u*4+m]: pl stride 40 == 8 mod 32 -> conflict-light both ways.
    __shared__ float xg2[TC][160];                 // 10.2 KB
    __shared__ __align__(16) float hbuf[4][12];    // 12-pad: float4-aligned rows
    __shared__ __align__(16) float wtl[D_IN * G4]; // 5.6 KB: Wt LDS copy
    __shared__ __align__(16) float biasl[G4];

    const int lane = threadIdx.x;
    const int b = (N_PATHS / 4 - 1) - blockIdx.x;  // longest-first (LPT)

    // uniform (scalar) path metadata
    const int p0 = perm[4 * b + 0], p1 = perm[4 * b + 1];
    const int p2 = perm[4 * b + 2], p3 = perm[4 * b + 3];
    const int l0 = last_idx[p0], l1 = last_idx[p1];
    const int l2 = last_idx[p2], l3 = last_idx[p3];
    const int wmax = max(max(l0, l1), max(l2, l3));

    // stage Wt + bias into LDS (once per block; ~90 float4 loads over 64 lanes)
    {
        const float4* wsrc = (const float4*)Wt;
#pragma unroll
        for (int k = 0; k < 6; ++k) {
            int idx = k * 64 + lane;
            if (idx < (D_IN * G4) / 4) *(float4*)&wtl[4 * idx] = wsrc[idx];
        }
        if (lane < G4 / 4) *(float4*)&biasl[4 * lane] = ((const float4*)bias)[lane];
    }

    // phase-1 ids: lane = tc*4 + pl  (keeps LDS write octets conflict-light)
    const int pl1 = lane & 3, tc1 = lane >> 2;
    // phase-2 ids
    const int pl2 = lane >> 3, j = lane & 7;
    const bool act2 = lane < 32;

    const int pg1 = pl1 == 0 ? p0 : pl1 == 1 ? p1 : pl1 == 2 ? p2 : p3;
    const int pg2 = pl2 == 0 ? p0 : pl2 == 1 ? p1 : pl2 == 2 ? p2 : p3;
    const int lst2 = pl2 == 0 ? l0 : pl2 == 1 ? l1 : pl2 == 2 ? l2 : l3;

    // preload W_hh rows {j, 8+j, 16+j, 24+j} -> 32 VGPRs (straight k-order;
    // whh layout is independent of the Wt unit-major permutation)
    float whh[4][8];
#pragma unroll
    for (int m = 0; m < 4; ++m) {
        const float4* r = (const float4*)(Whh + (m * 8 + j) * H_SZ);
        float4 a = r[0], c = r[1];
        whh[m][0] = a.x; whh[m][1] = a.y; whh[m][2] = a.z; whh[m][3] = a.w;
        whh[m][4] = c.x; whh[m][5] = c.y; whh[m][6] = c.z; whh[m][7] = c.w;
    }
    const float fcWj = fcW[j];

    float hval = 0.f, cval = 0.f, hlast = 0.f;
    if (act2) hbuf[pl2][j] = 0.f;   // h0 = 0 (read before first write in phase 2)

    const float* xrow_base = x + (size_t)pg1 * (T_STEPS * D_IN);
    const int nch = (wmax >> 4) + 1;  // truncate at per-wave max length

    // software pipeline: preload chunk 0's x row into registers
    float4 xv[11];
    {
        const float4* xr = (const float4*)(xrow_base + tc1 * D_IN);
#pragma unroll
        for (int q = 0; q < 11; ++q) xv[q] = xr[q];
    }

    for (int ch = 0; ch < nch; ++ch) {
        // ---------------- phase 1: xg = bias + x . Wt (weights from LDS) ----------------
        {
            float acc[32];
#pragma unroll
            for (int gq = 0; gq < 8; ++gq) {
                const float4 bv = *(const float4*)&biasl[4 * gq];
                acc[4 * gq + 0] = bv.x; acc[4 * gq + 1] = bv.y;
                acc[4 * gq + 2] = bv.z; acc[4 * gq + 3] = bv.w;
            }
#pragma unroll
            for (int q = 0; q < 11; ++q) {
                float4 v = xv[q];
#pragma unroll
                for (int r = 0; r < 4; ++r) {
                    const float xd = (r == 0) ? v.x : (r == 1) ? v.y : (r == 2) ? v.z : v.w;
                    const int d = 4 * q + r;
#pragma unroll
                    for (int gq = 0; gq < 8; ++gq) {
                        // uniform address across lanes -> LDS broadcast, conflict-free
                        const float4 w = *(const float4*)&wtl[d * G4 + 4 * gq];
                        acc[4 * gq + 0] = fmaf(w.x, xd, acc[4 * gq + 0]);
                        acc[4 * gq + 1] = fmaf(w.y, xd, acc[4 * gq + 1]);
                        acc[4 * gq + 2] = fmaf(w.z, xd, acc[4 * gq + 2]);
                        acc[4 * gq + 3] = fmaf(w.w, xd, acc[4 * gq + 3]);
                    }
                }
            }
#pragma unroll
            for (int k = 0; k < 8; ++k) {
                float4 v = make_float4(acc[4 * k], acc[4 * k + 1], acc[4 * k + 2], acc[4 * k + 3]);
                *(float4*)&xg2[tc1][pl1 * 40 + 4 * k] = v;
            }
        }
        // preload next chunk's x into registers; consumed next iteration, so the
        // HBM latency hides under phase 2 below. (uniform branch)
        if (ch + 1 < nch) {
            const float4* xr = (const float4*)(xrow_base + ((ch + 1) * TC + tc1) * D_IN);
#pragma unroll
            for (int q = 0; q < 11; ++q) xv[q] = xr[q];
        }
        // ---------------- phase 2: 16 recurrence steps ----------------
        if (act2) {
            const int t0 = ch * TC;
#pragma unroll
            for (int tt = 0; tt < TC; ++tt) {
                // one b128: (i,f,g,o) pre-acts for this (path,unit) — valid because
                // Wt/bias are unit-major permuted (acc[u*4+m])
                const float4 xg = *(const float4*)&xg2[tt][pl2 * 40 + 4 * j];
                const float4 h01 = *(const float4*)&hbuf[pl2][0];
                const float4 h23 = *(const float4*)&hbuf[pl2][4];
                const float xgc[4] = {xg.x, xg.y, xg.z, xg.w};
                float pre[4];
#pragma unroll
                for (int m = 0; m < 4; ++m) {
                    float p = xgc[m];
                    p = fmaf(whh[m][0], h01.x, p); p = fmaf(whh[m][1], h01.y, p);
                    p = fmaf(whh[m][2], h01.z, p); p = fmaf(whh[m][3], h01.w, p);
                    p = fmaf(whh[m][4], h23.x, p); p = fmaf(whh[m][5], h23.y, p);
                    p = fmaf(whh[m][6], h23.z, p); p = fmaf(whh[m][7], h23.w, p);
                    pre[m] = p;
                }
                const float ig = sigm_f(pre[0]);
                const float fg = sigm_f(pre[1]);
                const float gg = tanh_f(pre[2]);
                const float og = sigm_f(pre[3]);
                cval = fmaf(fg, cval, ig * gg);
                hval = og * tanh_f(cval);
                const int t = t0 + tt;
                hlast = (t == lst2) ? hval : hlast;
                hbuf[pl2][j] = hval;   // same-wave LDS: in-order, no barrier needed
            }
        }
    }

    if (act2) {
        float v = hlast * fcWj;            // per-path score = dot(h_last, fc_W)
        v += __shfl_xor(v, 1);
        v += __shfl_xor(v, 2);
        v += __shfl_xor(v, 4);
        if (j == 0) sout[pg2] = v;
    }
}

// ---------------- finalize: segment-sum + softmax over 1024 groups ----------------
__global__ void finalize_kernel(const float* __restrict__ s, const int* __restrict__ gid,
                                float* __restrict__ out) {
    __shared__ float seg[NGROUPS];
    __shared__ float red[16];
    const int tid = threadIdx.x;  // 1024
    seg[tid] = 0.f;
    __syncthreads();
#pragma unroll
    for (int k = 0; k < 8; ++k) {
        const int p = k * 1024 + tid;
        atomicAdd(&seg[gid[p]], s[p]);
    }
    __syncthreads();
    const float v = seg[tid];  // logit (fc_b cancels exactly in softmax)
    const int wid = tid >> 6, ln = tid & 63;
    // ---- max reduce ----
    float m = v;
#pragma unroll
    for (int o = 32; o >= 1; o >>= 1) m = fmaxf(m, __shfl_xor(m, o));
    if (ln == 0) red[wid] = m;
    __syncthreads();
    if (tid < 16) {
        float mm = red[tid];
#pragma unroll
        for (int o = 8; o >= 1; o >>= 1) mm = fmaxf(mm, __shfl_xor(mm, o));
        red[tid] = mm;
    }
    __syncthreads();
    const float vmax = red[0];
    __syncthreads();  // protect red[] reuse
    // ---- sum reduce ----
    const float e = __expf(v - vmax);
    float ss = e;
#pragma unroll
    for (int o = 32; o >= 1; o >>= 1) ss += __shfl_xor(ss, o);
    if (ln == 0) red[wid] = ss;
    __syncthreads();
    if (tid < 16) {
        float s2 = red[tid];
#pragma unroll
        for (int o = 8; o >= 1; o >>= 1) s2 += __shfl_xor(s2, o);
        red[tid] = s2;
    }
    __syncthreads();
    const float tot = red[0];
    out[tid] = e / tot;
}

extern "C" void kernel_launch(void* const* d_in, const int* in_sizes, int n_in,
                              void* d_out, int out_size, void* d_ws, size_t ws_size,
                              hipStream_t stream) {
    const float* x      = (const float*)d_in[0];
    const float* W_ih   = (const float*)d_in[1];
    const float* W_hh   = (const float*)d_in[2];
    const float* b_ih   = (const float*)d_in[3];
    const float* b_hh   = (const float*)d_in[4];
    const float* fcW    = (const float*)d_in[5];
    // d_in[6] = fc_b: constant shift of all logits -> cancels in softmax, skipped
    const int* last_idx = (const int*)d_in[7];
    const int* gid      = (const int*)d_in[8];

    float* wsf  = (float*)d_ws;
    float* Wt   = wsf;
    float* bias = wsf + 1408;
    int*   perm = (int*)(wsf + 1440);
    float* sarr = wsf + 1440 + 8192;
    float* out  = (float*)d_out;

    hipLaunchKernelGGL(prep_kernel, dim3(1), dim3(256), 0, stream,
                       W_ih, b_ih, b_hh, last_idx, Wt, bias, perm);
    hipLaunchKernelGGL(lstm_kernel, dim3(N_PATHS / 4), dim3(64), 0, stream,
                       x, W_hh, Wt, bias, fcW, last_idx, perm, sarr);
    hipLaunchKernelGGL(finalize_kernel, dim3(1), dim3(1024), 0, stream,
                       sarr, gid, out);
}

// Round 7
// 543.405 us; speedup vs baseline: 1.3848x; 1.3848x over previous
//
#include <hip/hip_runtime.h>

#define N_PATHS 8192
#define T_STEPS 256
#define D_IN    44
#define H_SZ    8
#define G4      32      // 4*H
#define NGROUPS 1024
#define TC      16      // timesteps per chunk

// ---------------- workspace layout (floats) ----------------
// [0, 1408)            Wt   : W_ih transposed+gate-permuted [d][u*4+m]
// [1408, 1440)         bias : b_ih + b_hh (gate-permuted, u*4+m)
// [1440, 1440+8192)    perm : path ids sorted by last_idx (int)
// [9632, 9632+8192)    s    : per-path score dot(h_last, fc_W)

__device__ __forceinline__ float sigm_f(float x) {
    return __builtin_amdgcn_rcpf(1.0f + __expf(-x));
}
__device__ __forceinline__ float tanh_f(float x) {
    return 1.0f - 2.0f * __builtin_amdgcn_rcpf(1.0f + __expf(2.0f * x));
}

// ---------------- prep: permuted transpose + counting sort by last_idx ----------------
__global__ void prep_kernel(const float* __restrict__ W_ih, const float* __restrict__ b_ih,
                            const float* __restrict__ b_hh, const int* __restrict__ last_idx,
                            float* __restrict__ Wt, float* __restrict__ bias,
                            int* __restrict__ perm) {
    __shared__ int hist[256];
    __shared__ int off[256];
    const int tid = threadIdx.x;  // 256 threads
    hist[tid] = 0;
    // transpose W_ih [32][44] -> Wt [44][32], gate index permuted to UNIT-MAJOR:
    // row g = m*8+u  ->  column u*4+m. REQUIRED by phase-2's float4 read at 4*j.
    for (int idx = tid; idx < G4 * D_IN; idx += 256) {
        int g = idx / D_IN, d = idx - g * D_IN;
        int gp = ((g & 7) << 2) | (g >> 3);   // u*4 + m
        Wt[d * G4 + gp] = W_ih[idx];
    }
    if (tid < G4) {
        int gp = ((tid & 7) << 2) | (tid >> 3);
        bias[gp] = b_ih[tid] + b_hh[tid];
    }
    __syncthreads();
    for (int k = 0; k < N_PATHS / 256; ++k)
        atomicAdd(&hist[last_idx[k * 256 + tid]], 1);
    __syncthreads();
    if (tid == 0) {  // serial exclusive scan over 256 bins: trivial cost
        int run = 0;
        for (int i = 0; i < 256; ++i) { off[i] = run; run += hist[i]; }
    }
    __syncthreads();
    for (int k = 0; k < N_PATHS / 256; ++k) {
        int p = k * 256 + tid;
        int b = last_idx[p];
        int pos = atomicAdd(&off[b], 1);
        perm[pos] = p;   // order within a length-bin is arbitrary; harmless
    }
}

// ---------------- main fused LSTM kernel ----------------
// 1 wave per block, 4 length-sorted paths per wave, no __syncthreads needed
// (single wave: LDS ops complete in order within a wave).
// Round-6 CONFIRMED the instruction-count theory (issue-slots/chunk down 2.8x
// with LDS-broadcast weights) but the unpinned scheduler hoisted dozens of the
// 352 ds_read_b128 per chunk, blowing the live set to the 256-VGPR arch cap and
// spilling acc/xv (WRITE_SIZE 70 MB, VALUBusy 17%). FIX: sched_barrier(0) after
// each d-iteration caps the window at 8 in-flight w-reads (32 VGPR) + 32 FMAs.
__global__ __launch_bounds__(64, 1)
void lstm_kernel(const float* __restrict__ x, const float* __restrict__ Whh,
                 const float* __restrict__ Wt, const float* __restrict__ bias,
                 const float* __restrict__ fcW, const int* __restrict__ last_idx,
                 const int* __restrict__ perm, float* __restrict__ sout) {
    // xg2[tc][pl*40 + u*4+m]: pl stride 40 == 8 mod 32 -> conflict-light both ways.
    __shared__ float xg2[TC][160];                 // 10.2 KB
    __shared__ __align__(16) float hbuf[4][12];    // 12-pad: float4-aligned rows
    __shared__ __align__(16) float wtl[D_IN * G4]; // 5.6 KB: Wt LDS copy
    __shared__ __align__(16) float biasl[G4];

    const int lane = threadIdx.x;
    const int b = (N_PATHS / 4 - 1) - blockIdx.x;  // longest-first (LPT)

    // uniform (scalar) path metadata
    const int p0 = perm[4 * b + 0], p1 = perm[4 * b + 1];
    const int p2 = perm[4 * b + 2], p3 = perm[4 * b + 3];
    const int l0 = last_idx[p0], l1 = last_idx[p1];
    const int l2 = last_idx[p2], l3 = last_idx[p3];
    const int wmax = max(max(l0, l1), max(l2, l3));

    // stage Wt + bias into LDS (once per block; ~90 float4 loads over 64 lanes)
    {
        const float4* wsrc = (const float4*)Wt;
#pragma unroll
        for (int k = 0; k < 6; ++k) {
            int idx = k * 64 + lane;
            if (idx < (D_IN * G4) / 4) *(float4*)&wtl[4 * idx] = wsrc[idx];
        }
        if (lane < G4 / 4) *(float4*)&biasl[4 * lane] = ((const float4*)bias)[lane];
    }

    // phase-1 ids: lane = tc*4 + pl  (keeps LDS write octets conflict-light)
    const int pl1 = lane & 3, tc1 = lane >> 2;
    // phase-2 ids
    const int pl2 = lane >> 3, j = lane & 7;
    const bool act2 = lane < 32;

    const int pg1 = pl1 == 0 ? p0 : pl1 == 1 ? p1 : pl1 == 2 ? p2 : p3;
    const int pg2 = pl2 == 0 ? p0 : pl2 == 1 ? p1 : pl2 == 2 ? p2 : p3;
    const int lst2 = pl2 == 0 ? l0 : pl2 == 1 ? l1 : pl2 == 2 ? l2 : l3;

    // preload W_hh rows {j, 8+j, 16+j, 24+j} -> 32 VGPRs (straight k-order;
    // whh layout is independent of the Wt unit-major permutation)
    float whh[4][8];
#pragma unroll
    for (int m = 0; m < 4; ++m) {
        const float4* r = (const float4*)(Whh + (m * 8 + j) * H_SZ);
        float4 a = r[0], c = r[1];
        whh[m][0] = a.x; whh[m][1] = a.y; whh[m][2] = a.z; whh[m][3] = a.w;
        whh[m][4] = c.x; whh[m][5] = c.y; whh[m][6] = c.z; whh[m][7] = c.w;
    }
    const float fcWj = fcW[j];

    float hval = 0.f, cval = 0.f, hlast = 0.f;
    if (act2) hbuf[pl2][j] = 0.f;   // h0 = 0 (read before first write in phase 2)

    const float* xrow_base = x + (size_t)pg1 * (T_STEPS * D_IN);
    const int nch = (wmax >> 4) + 1;  // truncate at per-wave max length

    // software pipeline: preload chunk 0's x row into registers
    float4 xv[11];
    {
        const float4* xr = (const float4*)(xrow_base + tc1 * D_IN);
#pragma unroll
        for (int q = 0; q < 11; ++q) xv[q] = xr[q];
    }

    for (int ch = 0; ch < nch; ++ch) {
        // ---------------- phase 1: xg = bias + x . Wt (weights from LDS) ----------------
        {
            float acc[32];
#pragma unroll
            for (int gq = 0; gq < 8; ++gq) {
                const float4 bv = *(const float4*)&biasl[4 * gq];
                acc[4 * gq + 0] = bv.x; acc[4 * gq + 1] = bv.y;
                acc[4 * gq + 2] = bv.z; acc[4 * gq + 3] = bv.w;
            }
#pragma unroll
            for (int q = 0; q < 11; ++q) {
                float4 v = xv[q];
#pragma unroll
                for (int r = 0; r < 4; ++r) {
                    const float xd = (r == 0) ? v.x : (r == 1) ? v.y : (r == 2) ? v.z : v.w;
                    const int d = 4 * q + r;
#pragma unroll
                    for (int gq = 0; gq < 8; ++gq) {
                        // uniform address across lanes -> LDS broadcast, conflict-free
                        const float4 w = *(const float4*)&wtl[d * G4 + 4 * gq];
                        acc[4 * gq + 0] = fmaf(w.x, xd, acc[4 * gq + 0]);
                        acc[4 * gq + 1] = fmaf(w.y, xd, acc[4 * gq + 1]);
                        acc[4 * gq + 2] = fmaf(w.z, xd, acc[4 * gq + 2]);
                        acc[4 * gq + 3] = fmaf(w.w, xd, acc[4 * gq + 3]);
                    }
                    // Cap the scheduling window: at most 8 w-reads (32 VGPR) in
                    // flight. Without this, the pre-RA scheduler hoists ds_reads
                    // across d-iterations until the live set hits the 256-VGPR
                    // cap and spills acc/xv (round-6: WRITE_SIZE 70 MB).
                    __builtin_amdgcn_sched_barrier(0);
                }
            }
#pragma unroll
            for (int k = 0; k < 8; ++k) {
                float4 v = make_float4(acc[4 * k], acc[4 * k + 1], acc[4 * k + 2], acc[4 * k + 3]);
                *(float4*)&xg2[tc1][pl1 * 40 + 4 * k] = v;
            }
        }
        // preload next chunk's x into registers; consumed next iteration, so the
        // HBM latency hides under phase 2 below. (uniform branch)
        if (ch + 1 < nch) {
            const float4* xr = (const float4*)(xrow_base + ((ch + 1) * TC + tc1) * D_IN);
#pragma unroll
            for (int q = 0; q < 11; ++q) xv[q] = xr[q];
        }
        // ---------------- phase 2: 16 recurrence steps ----------------
        if (act2) {
            const int t0 = ch * TC;
#pragma unroll
            for (int tt = 0; tt < TC; ++tt) {
                // one b128: (i,f,g,o) pre-acts for this (path,unit) — valid because
                // Wt/bias are unit-major permuted (acc[u*4+m])
                const float4 xg = *(const float4*)&xg2[tt][pl2 * 40 + 4 * j];
                const float4 h01 = *(const float4*)&hbuf[pl2][0];
                const float4 h23 = *(const float4*)&hbuf[pl2][4];
                const float xgc[4] = {xg.x, xg.y, xg.z, xg.w};
                float pre[4];
#pragma unroll
                for (int m = 0; m < 4; ++m) {
                    float p = xgc[m];
                    p = fmaf(whh[m][0], h01.x, p); p = fmaf(whh[m][1], h01.y, p);
                    p = fmaf(whh[m][2], h01.z, p); p = fmaf(whh[m][3], h01.w, p);
                    p = fmaf(whh[m][4], h23.x, p); p = fmaf(whh[m][5], h23.y, p);
                    p = fmaf(whh[m][6], h23.z, p); p = fmaf(whh[m][7], h23.w, p);
                    pre[m] = p;
                }
                const float ig = sigm_f(pre[0]);
                const float fg = sigm_f(pre[1]);
                const float gg = tanh_f(pre[2]);
                const float og = sigm_f(pre[3]);
                cval = fmaf(fg, cval, ig * gg);
                hval = og * tanh_f(cval);
                const int t = t0 + tt;
                hlast = (t == lst2) ? hval : hlast;
                hbuf[pl2][j] = hval;   // same-wave LDS: in-order, no barrier needed
            }
        }
    }

    if (act2) {
        float v = hlast * fcWj;            // per-path score = dot(h_last, fc_W)
        v += __shfl_xor(v, 1);
        v += __shfl_xor(v, 2);
        v += __shfl_xor(v, 4);
        if (j == 0) sout[pg2] = v;
    }
}

// ---------------- finalize: segment-sum + softmax over 1024 groups ----------------
__global__ void finalize_kernel(const float* __restrict__ s, const int* __restrict__ gid,
                                float* __restrict__ out) {
    __shared__ float seg[NGROUPS];
    __shared__ float red[16];
    const int tid = threadIdx.x;  // 1024
    seg[tid] = 0.f;
    __syncthreads();
#pragma unroll
    for (int k = 0; k < 8; ++k) {
        const int p = k * 1024 + tid;
        atomicAdd(&seg[gid[p]], s[p]);
    }
    __syncthreads();
    const float v = seg[tid];  // logit (fc_b cancels exactly in softmax)
    const int wid = tid >> 6, ln = tid & 63;
    // ---- max reduce ----
    float m = v;
#pragma unroll
    for (int o = 32; o >= 1; o >>= 1) m = fmaxf(m, __shfl_xor(m, o));
    if (ln == 0) red[wid] = m;
    __syncthreads();
    if (tid < 16) {
        float mm = red[tid];
#pragma unroll
        for (int o = 8; o >= 1; o >>= 1) mm = fmaxf(mm, __shfl_xor(mm, o));
        red[tid] = mm;
    }
    __syncthreads();
    const float vmax = red[0];
    __syncthreads();  // protect red[] reuse
    // ---- sum reduce ----
    const float e = __expf(v - vmax);
    float ss = e;
#pragma unroll
    for (int o = 32; o >= 1; o >>= 1) ss += __shfl_xor(ss, o);
    if (ln == 0) red[wid] = ss;
    __syncthreads();
    if (tid < 16) {
        float s2 = red[tid];
#pragma unroll
        for (int o = 8; o >= 1; o >>= 1) s2 += __shfl_xor(s2, o);
        red[tid] = s2;
    }
    __syncthreads();
    const float tot = red[0];
    out[tid] = e / tot;
}

extern "C" void kernel_launch(void* const* d_in, const int* in_sizes, int n_in,
                              void* d_out, int out_size, void* d_ws, size_t ws_size,
                              hipStream_t stream) {
    const float* x      = (const float*)d_in[0];
    const float* W_ih   = (const float*)d_in[1];
    const float* W_hh   = (const float*)d_in[2];
    const float* b_ih   = (const float*)d_in[3];
    const float* b_hh   = (const float*)d_in[4];
    const float* fcW    = (const float*)d_in[5];
    // d_in[6] = fc_b: constant shift of all logits -> cancels in softmax, skipped
    const int* last_idx = (const int*)d_in[7];
    const int* gid      = (const int*)d_in[8];

    float* wsf  = (float*)d_ws;
    float* Wt   = wsf;
    float* bias = wsf + 1408;
    int*   perm = (int*)(wsf + 1440);
    float* sarr = wsf + 1440 + 8192;
    float* out  = (float*)d_out;

    hipLaunchKernelGGL(prep_kernel, dim3(1), dim3(256), 0, stream,
                       W_ih, b_ih, b_hh, last_idx, Wt, bias, perm);
    hipLaunchKernelGGL(lstm_kernel, dim3(N_PATHS / 4), dim3(64), 0, stream,
                       x, W_hh, Wt, bias, fcW, last_idx, perm, sarr);
    hipLaunchKernelGGL(finalize_kernel, dim3(1), dim3(1024), 0, stream,
                       sarr, gid, out);
}

// Round 8
// 535.937 us; speedup vs baseline: 1.4041x; 1.0139x over previous
//
#include <hip/hip_runtime.h>

#define N_PATHS 8192
#define T_STEPS 256
#define D_IN    44
#define H_SZ    8
#define G4      32      // 4*H
#define NGROUPS 1024
#define TC      16      // timesteps per chunk

// ---------------- workspace layout (floats) ----------------
// [0, 1408)            Wt   : W_ih transposed+gate-permuted [d][u*4+m]
// [1408, 1440)         bias : b_ih + b_hh (gate-permuted, u*4+m)
// [1440, 1440+8192)    perm : path ids sorted by last_idx (int)
// [9632, 9632+8192)    s    : per-path score dot(h_last, fc_W)

__device__ __forceinline__ float sigm_f(float x) {
    return __builtin_amdgcn_rcpf(1.0f + __expf(-x));
}
__device__ __forceinline__ float tanh_f(float x) {
    return 1.0f - 2.0f * __builtin_amdgcn_rcpf(1.0f + __expf(2.0f * x));
}

// ---------------- prep: permuted transpose + counting sort by last_idx ----------------
__global__ void prep_kernel(const float* __restrict__ W_ih, const float* __restrict__ b_ih,
                            const float* __restrict__ b_hh, const int* __restrict__ last_idx,
                            float* __restrict__ Wt, float* __restrict__ bias,
                            int* __restrict__ perm) {
    __shared__ int hist[256];
    __shared__ int off[256];
    const int tid = threadIdx.x;  // 256 threads
    hist[tid] = 0;
    // transpose W_ih [32][44] -> Wt [44][32], gate index permuted to UNIT-MAJOR:
    // row g = m*8+u  ->  column u*4+m. REQUIRED by phase-2's float4 read at 4*j.
    for (int idx = tid; idx < G4 * D_IN; idx += 256) {
        int g = idx / D_IN, d = idx - g * D_IN;
        int gp = ((g & 7) << 2) | (g >> 3);   // u*4 + m
        Wt[d * G4 + gp] = W_ih[idx];
    }
    if (tid < G4) {
        int gp = ((tid & 7) << 2) | (tid >> 3);
        bias[gp] = b_ih[tid] + b_hh[tid];
    }
    __syncthreads();
    for (int k = 0; k < N_PATHS / 256; ++k)
        atomicAdd(&hist[last_idx[k * 256 + tid]], 1);
    __syncthreads();
    if (tid == 0) {  // serial exclusive scan over 256 bins: trivial cost
        int run = 0;
        for (int i = 0; i < 256; ++i) { off[i] = run; run += hist[i]; }
    }
    __syncthreads();
    for (int k = 0; k < N_PATHS / 256; ++k) {
        int p = k * 256 + tid;
        int b = last_idx[p];
        int pos = atomicAdd(&off[b], 1);
        perm[pos] = p;   // order within a length-bin is arbitrary; harmless
    }
}

// ---------------- main fused LSTM kernel: producer/consumer wave pair ----------------
// 2 waves per block, 4 length-sorted paths per block.
// Wave 0 (producer): xg GEMM for chunk ch+1 (LDS-broadcast weights, same body as
//   round-7) into double-buffered xg2[ch&1].
// Wave 1 (consumer): 16-step recurrence for chunk ch (same body as round-7,
//   hbuf same-wave exchange).
// Wall time per chunk = max(GEMM, REC) instead of their sum (round-7 paid the
// sum serially in one wave). Handshake: producer syncs at loop bottom, consumer
// at loop top -> producer writes buf[ch&1] while consumer reads buf[(ch-1)&1];
// barrier count matches (nch each + 1 staging barrier).
__global__ __launch_bounds__(128, 2)
void lstm_kernel(const float* __restrict__ x, const float* __restrict__ Whh,
                 const float* __restrict__ Wt, const float* __restrict__ bias,
                 const float* __restrict__ fcW, const int* __restrict__ last_idx,
                 const int* __restrict__ perm, float* __restrict__ sout) {
    // xg2[buf][tc][pl*40 + u*4+m]: pl stride 40 == 8 mod 32 -> conflict-light.
    __shared__ float xg2[2][TC][160];              // 20.5 KB (double-buffered)
    __shared__ __align__(16) float hbuf[4][12];    // 12-pad: float4-aligned rows
    __shared__ __align__(16) float wtl[D_IN * G4]; // 5.6 KB: Wt LDS copy
    __shared__ __align__(16) float biasl[G4];

    const int tid = threadIdx.x;      // 0..127
    const int lane = tid & 63;
    const int w = tid >> 6;           // 0 = producer, 1 = consumer
    const int b = (N_PATHS / 4 - 1) - blockIdx.x;  // longest-first (LPT)

    // uniform (scalar) path metadata (both waves)
    const int p0 = perm[4 * b + 0], p1 = perm[4 * b + 1];
    const int p2 = perm[4 * b + 2], p3 = perm[4 * b + 3];
    const int l0 = last_idx[p0], l1 = last_idx[p1];
    const int l2 = last_idx[p2], l3 = last_idx[p3];
    const int wmax = max(max(l0, l1), max(l2, l3));
    const int nch = (wmax >> 4) + 1;  // truncate at per-wave max length

    // stage Wt + bias into LDS cooperatively (128 threads, 352 float4s)
    {
        const float4* wsrc = (const float4*)Wt;
#pragma unroll
        for (int k = 0; k < 3; ++k) {
            int idx = k * 128 + tid;
            if (idx < (D_IN * G4) / 4) *(float4*)&wtl[4 * idx] = wsrc[idx];
        }
        if (tid < G4 / 4) *(float4*)&biasl[4 * tid] = ((const float4*)bias)[tid];
    }
    __syncthreads();   // staging barrier (1 per wave)

    if (w == 0) {
        // ================= producer wave: xg GEMM =================
        const int pl1 = lane & 3, tc1 = lane >> 2;
        const int pg1 = pl1 == 0 ? p0 : pl1 == 1 ? p1 : pl1 == 2 ? p2 : p3;
        const float* xrow_base = x + (size_t)pg1 * (T_STEPS * D_IN);

        float4 xv[11];
        {
            const float4* xr = (const float4*)(xrow_base + tc1 * D_IN);
#pragma unroll
            for (int q = 0; q < 11; ++q) xv[q] = xr[q];
        }

        for (int ch = 0; ch < nch; ++ch) {
            float acc[32];
#pragma unroll
            for (int gq = 0; gq < 8; ++gq) {
                const float4 bv = *(const float4*)&biasl[4 * gq];
                acc[4 * gq + 0] = bv.x; acc[4 * gq + 1] = bv.y;
                acc[4 * gq + 2] = bv.z; acc[4 * gq + 3] = bv.w;
            }
#pragma unroll
            for (int q = 0; q < 11; ++q) {
                float4 v = xv[q];
#pragma unroll
                for (int r = 0; r < 4; ++r) {
                    const float xd = (r == 0) ? v.x : (r == 1) ? v.y : (r == 2) ? v.z : v.w;
                    const int d = 4 * q + r;
#pragma unroll
                    for (int gq = 0; gq < 8; ++gq) {
                        // uniform address across lanes -> LDS broadcast, conflict-free
                        const float4 ww = *(const float4*)&wtl[d * G4 + 4 * gq];
                        acc[4 * gq + 0] = fmaf(ww.x, xd, acc[4 * gq + 0]);
                        acc[4 * gq + 1] = fmaf(ww.y, xd, acc[4 * gq + 1]);
                        acc[4 * gq + 2] = fmaf(ww.z, xd, acc[4 * gq + 2]);
                        acc[4 * gq + 3] = fmaf(ww.w, xd, acc[4 * gq + 3]);
                    }
                    // Cap the scheduling window (round-6 lesson): at most 8
                    // in-flight w-reads; prevents RA blowup + spill.
                    __builtin_amdgcn_sched_barrier(0);
                }
            }
#pragma unroll
            for (int k = 0; k < 8; ++k) {
                float4 v = make_float4(acc[4 * k], acc[4 * k + 1], acc[4 * k + 2], acc[4 * k + 3]);
                *(float4*)&xg2[ch & 1][tc1][pl1 * 40 + 4 * k] = v;
            }
            // prefetch next chunk's x; drains at the barrier below, mostly
            // overlapped with the consumer handshake wait
            if (ch + 1 < nch) {
                const float4* xr = (const float4*)(xrow_base + ((ch + 1) * TC + tc1) * D_IN);
#pragma unroll
                for (int q = 0; q < 11; ++q) xv[q] = xr[q];
            }
            __syncthreads();   // publish xg2[ch&1]
        }
    } else {
        // ================= consumer wave: recurrence =================
        const int pl2 = lane >> 3, j = lane & 7;
        const bool act2 = lane < 32;
        const int pg2 = pl2 == 0 ? p0 : pl2 == 1 ? p1 : pl2 == 2 ? p2 : p3;
        const int lst2 = pl2 == 0 ? l0 : pl2 == 1 ? l1 : pl2 == 2 ? l2 : l3;

        // preload W_hh rows {j, 8+j, 16+j, 24+j} -> 32 VGPRs (straight k-order)
        float whh[4][8];
#pragma unroll
        for (int m = 0; m < 4; ++m) {
            const float4* r = (const float4*)(Whh + (m * 8 + j) * H_SZ);
            float4 a = r[0], c = r[1];
            whh[m][0] = a.x; whh[m][1] = a.y; whh[m][2] = a.z; whh[m][3] = a.w;
            whh[m][4] = c.x; whh[m][5] = c.y; whh[m][6] = c.z; whh[m][7] = c.w;
        }
        const float fcWj = fcW[j];

        float hval = 0.f, cval = 0.f, hlast = 0.f;
        if (act2) hbuf[pl2][j] = 0.f;   // h0 = 0 (same-wave read later)

        for (int ch = 0; ch < nch; ++ch) {
            __syncthreads();   // wait for xg2[ch&1]
            if (act2) {
                const int t0 = ch * TC;
#pragma unroll
                for (int tt = 0; tt < TC; ++tt) {
                    // one b128: (i,f,g,o) pre-acts for this (path,unit) — valid
                    // because Wt/bias are unit-major permuted (acc[u*4+m])
                    const float4 xg = *(const float4*)&xg2[ch & 1][tt][pl2 * 40 + 4 * j];
                    const float4 h01 = *(const float4*)&hbuf[pl2][0];
                    const float4 h23 = *(const float4*)&hbuf[pl2][4];
                    const float xgc[4] = {xg.x, xg.y, xg.z, xg.w};
                    float pre[4];
#pragma unroll
                    for (int m = 0; m < 4; ++m) {
                        float p = xgc[m];
                        p = fmaf(whh[m][0], h01.x, p); p = fmaf(whh[m][1], h01.y, p);
                        p = fmaf(whh[m][2], h01.z, p); p = fmaf(whh[m][3], h01.w, p);
                        p = fmaf(whh[m][4], h23.x, p); p = fmaf(whh[m][5], h23.y, p);
                        p = fmaf(whh[m][6], h23.z, p); p = fmaf(whh[m][7], h23.w, p);
                        pre[m] = p;
                    }
                    const float ig = sigm_f(pre[0]);
                    const float fg = sigm_f(pre[1]);
                    const float gg = tanh_f(pre[2]);
                    const float og = sigm_f(pre[3]);
                    cval = fmaf(fg, cval, ig * gg);
                    hval = og * tanh_f(cval);
                    const int t = t0 + tt;
                    hlast = (t == lst2) ? hval : hlast;
                    hbuf[pl2][j] = hval;   // same-wave LDS: in-order, no barrier
                }
            }
        }

        if (act2) {
            float v = hlast * fcWj;            // per-path score = dot(h_last, fc_W)
            v += __shfl_xor(v, 1);
            v += __shfl_xor(v, 2);
            v += __shfl_xor(v, 4);
            if (j == 0) sout[pg2] = v;
        }
    }
}

// ---------------- finalize: segment-sum + softmax over 1024 groups ----------------
__global__ void finalize_kernel(const float* __restrict__ s, const int* __restrict__ gid,
                                float* __restrict__ out) {
    __shared__ float seg[NGROUPS];
    __shared__ float red[16];
    const int tid = threadIdx.x;  // 1024
    seg[tid] = 0.f;
    __syncthreads();
#pragma unroll
    for (int k = 0; k < 8; ++k) {
        const int p = k * 1024 + tid;
        atomicAdd(&seg[gid[p]], s[p]);
    }
    __syncthreads();
    const float v = seg[tid];  // logit (fc_b cancels exactly in softmax)
    const int wid = tid >> 6, ln = tid & 63;
    // ---- max reduce ----
    float m = v;
#pragma unroll
    for (int o = 32; o >= 1; o >>= 1) m = fmaxf(m, __shfl_xor(m, o));
    if (ln == 0) red[wid] = m;
    __syncthreads();
    if (tid < 16) {
        float mm = red[tid];
#pragma unroll
        for (int o = 8; o >= 1; o >>= 1) mm = fmaxf(mm, __shfl_xor(mm, o));
        red[tid] = mm;
    }
    __syncthreads();
    const float vmax = red[0];
    __syncthreads();  // protect red[] reuse
    // ---- sum reduce ----
    const float e = __expf(v - vmax);
    float ss = e;
#pragma unroll
    for (int o = 32; o >= 1; o >>= 1) ss += __shfl_xor(ss, o);
    if (ln == 0) red[wid] = ss;
    __syncthreads();
    if (tid < 16) {
        float s2 = red[tid];
#pragma unroll
        for (int o = 8; o >= 1; o >>= 1) s2 += __shfl_xor(s2, o);
        red[tid] = s2;
    }
    __syncthreads();
    const float tot = red[0];
    out[tid] = e / tot;
}

extern "C" void kernel_launch(void* const* d_in, const int* in_sizes, int n_in,
                              void* d_out, int out_size, void* d_ws, size_t ws_size,
                              hipStream_t stream) {
    const float* x      = (const float*)d_in[0];
    const float* W_ih   = (const float*)d_in[1];
    const float* W_hh   = (const float*)d_in[2];
    const float* b_ih   = (const float*)d_in[3];
    const float* b_hh   = (const float*)d_in[4];
    const float* fcW    = (const float*)d_in[5];
    // d_in[6] = fc_b: constant shift of all logits -> cancels in softmax, skipped
    const int* last_idx = (const int*)d_in[7];
    const int* gid      = (const int*)d_in[8];

    float* wsf  = (float*)d_ws;
    float* Wt   = wsf;
    float* bias = wsf + 1408;
    int*   perm = (int*)(wsf + 1440);
    float* sarr = wsf + 1440 + 8192;
    float* out  = (float*)d_out;

    hipLaunchKernelGGL(prep_kernel, dim3(1), dim3(256), 0, stream,
                       W_ih, b_ih, b_hh, last_idx, Wt, bias, perm);
    hipLaunchKernelGGL(lstm_kernel, dim3(N_PATHS / 4), dim3(128), 0, stream,
                       x, W_hh, Wt, bias, fcW, last_idx, perm, sarr);
    hipLaunchKernelGGL(finalize_kernel, dim3(1), dim3(1024), 0, stream,
                       sarr, gid, out);
}